// Round 5
// baseline (481.773 us; speedup 1.0000x reference)
//
#include <hip/hip_runtime.h>
#include <cstdint>
#include <cmath>

// Sudoku iterative-solver, one wave (64 lanes) per board.
// R1/R2 validated: 21 distinct f-rows, dist_row mapping, 3-row update set,
//   first-max tie-break via ballot+ctz, cached-row reuse.
// R3/R4 lesson: decisions sit on near-ties (gap ~1e-6); any fp32 reorder can
//   flip one vs the np-fp64 reference (R2: benign 4.9e-4; R3: 2.8e-2 FAIL).
// R5: keep R3's fast structure, add a NEAR-TIE SAFETY NET: if the cross-cell
//   argmax candidates span >1 row, or the winning row's digit gap < 1e-3,
//   re-resolve those rows in fp64 from exact integer counts. fp64-vs-np
//   error ~1e-15 => decisions match np deterministically.

__device__ __forceinline__ void wave_fence() {
  asm volatile("s_waitcnt lgkmcnt(0)" ::: "memory");
}
__device__ __forceinline__ void cbar() { asm volatile("" ::: "memory"); }

template <int CTRL>
__device__ __forceinline__ float dppf(float v) {
  return __int_as_float(__builtin_amdgcn_update_dpp(
      0, __float_as_int(v), CTRL, 0xF, 0xF, true));
}
template <int IMM>
__device__ __forceinline__ float swzf(float v) {
  return __int_as_float(__builtin_amdgcn_ds_swizzle(__float_as_int(v), IMM));
}
__device__ __forceinline__ float redmax64(float v) {
  v = fmaxf(v, dppf<0xB1>(v));
  v = fmaxf(v, dppf<0x4E>(v));
  v = fmaxf(v, swzf<0x101F>(v));
  v = fmaxf(v, dppf<0x128>(v));
  v = fmaxf(v, swzf<0x401F>(v));
  v = fmaxf(v, __shfl_xor(v, 32));
  return v;
}

__device__ __forceinline__ int dist_row(int i) {
  int r = i / 27;
  int t = i - 27 * r;
  if (r == 0) return t / 3;
  if (r == 1) return 9 + (t % 3);
  return 12 + 3 * (t / 9) + (t % 3);
}

// uniform-index select from a register array (b0d..b3d = bits of idx, idx<=8)
#define SEL9C(A, B)                                                          \
  (b3d ? A[(B) + 8]                                                          \
       : (b2d ? (b1d ? (b0d ? A[(B) + 7] : A[(B) + 6])                       \
                     : (b0d ? A[(B) + 5] : A[(B) + 4]))                      \
              : (b1d ? (b0d ? A[(B) + 3] : A[(B) + 2])                       \
                     : (b0d ? A[(B) + 1] : A[(B) + 0]))))

__global__ __launch_bounds__(64, 2)
void sudoku_solver(const float* __restrict__ x, const float* __restrict__ W1g,
                   const float* __restrict__ W2g, float* __restrict__ out) {
  __shared__ float  preL[21][128];   // fp32 pre-activations (fast path)
  __shared__ float  W2s[9][132];     // W2 rows (slow-path dot; padded)
  __shared__ float  sful[21][12];    // cached fast softmax rows
  __shared__ float  cnt[3][9][12];   // exact integer digit counts (fp32)
  __shared__ float  rgapL[24];       // per-row digit-argmax gap
  __shared__ double h64[128];        // slow-path fp64 h scratch
  __shared__ int    digc[81];

  const int lane = threadIdx.x;
  const int b = blockIdx.x;
  const float* xb = x + b * 729;
  float* ob = out + b * 729;

  for (int idx = lane; idx < 1152; idx += 64)
    W2s[idx >> 7][idx & 127] = W2g[idx];

  float w1a[27], w1b[27];
  #pragma unroll
  for (int c = 0; c < 27; ++c) {
    w1a[c] = W1g[lane * 27 + c];
    w1b[c] = W1g[(lane + 64) * 27 + c];
  }
  float w2A[9], w2B[9];
  #pragma unroll
  for (int d = 0; d < 9; ++d) {
    w2A[d] = W2g[d * 128 + lane];
    w2B[d] = W2g[d * 128 + 64 + lane];
  }

  for (int idx = lane; idx < 3 * 9 * 12; idx += 64)
    ((float*)cnt)[idx] = 0.f;

  bool eA, eB = false;
  {
    float v[9]; int dg = -1;
    #pragma unroll
    for (int e = 0; e < 9; ++e) v[e] = xb[lane * 9 + e];
    #pragma unroll
    for (int e = 0; e < 9; ++e) { if (v[e] > 0.5f) dg = e; ob[lane * 9 + e] = v[e]; }
    eA = (dg < 0); digc[lane] = dg;
    if (lane < 17) {
      const int i2 = 64 + lane;
      float w[9]; int dg2 = -1;
      #pragma unroll
      for (int e = 0; e < 9; ++e) w[e] = xb[i2 * 9 + e];
      #pragma unroll
      for (int e = 0; e < 9; ++e) { if (w[e] > 0.5f) dg2 = e; ob[i2 * 9 + e] = w[e]; }
      eB = (dg2 < 0); digc[i2] = dg2;
    }
  }
  const int distA = dist_row(lane);
  const int distB = (lane < 17) ? dist_row(64 + lane) : 255;
  const int rr3 = lane >> 4;
  const int dl  = lane & 15;
  const bool sv = (rr3 < 3) && (dl < 9);
  const bool sb0 = dl & 1, sb1 = dl & 2, sb2 = dl & 4, sb3 = dl & 8;
  const int bpaddr = ((lane ^ 32) & 63) << 2;
  wave_fence();

  if (lane < 27) {
    const int g = lane / 9, gi = lane - 9 * g;
    float c9[9];
    #pragma unroll
    for (int e = 0; e < 9; ++e) c9[e] = 0.f;
    #pragma unroll
    for (int k = 0; k < 9; ++k) {
      int cell;
      if (g == 0)      cell = gi * 9 + k;
      else if (g == 1) cell = k * 9 + gi;
      else             cell = (gi / 3) * 27 + (gi % 3) * 3 + (k / 3) * 9 + (k % 3);
      const int dg = digc[cell];
      #pragma unroll
      for (int e = 0; e < 9; ++e) c9[e] += (dg == e) ? 1.f : 0.f;
    }
    #pragma unroll
    for (int e = 0; e < 9; ++e) cnt[g][gi][e] = c9[e];
  }
  wave_fence();

  float myscoreA = 0.f, myscoreB = 0.f;
  int mydigA = 0, mydigB = 0;
  float hA[3], hB[3];

  auto grp_map = [](int u, int& g, int& gia, int& gib, int& gic) {
    if (u < 9)       { g = 0; gia = gib = gic = u; }
    else if (u < 12) { g = 1; gia = 3 * (u - 9); gib = gia + 1; gic = gia + 2; }
    else             { g = 2; gia = gib = gic = u - 12; }
  };

  // ---- fast Phase D (fp32): register GEMV + butterfly + replicated softmax ----
  auto phaseD = [&](int u0, int u1, int u2) {
    float P[3][9];
    #pragma unroll
    for (int rr = 0; rr < 3; ++rr)
      #pragma unroll
      for (int dd = 0; dd < 9; ++dd)
        P[rr][dd] = fmaf(hA[rr], w2A[dd], hB[rr] * w2B[dd]);
    #pragma unroll
    for (int rr = 0; rr < 3; ++rr)
      #pragma unroll
      for (int dd = 0; dd < 9; ++dd) {
        float v = P[rr][dd];
        v += swzf<0x401F>(v);
        v += __int_as_float(__builtin_amdgcn_ds_bpermute(bpaddr, __float_as_int(v)));
        v = v + dppf<0x121>(v);
        v = v + dppf<0x122>(v);
        v = v + dppf<0x124>(v);
        v = v + dppf<0x128>(v);
        P[rr][dd] = v;
      }
    float q[9];
    #pragma unroll
    for (int dd = 0; dd < 9; ++dd)
      q[dd] = (rr3 >= 2) ? P[2][dd] : ((rr3 == 1) ? P[1][dd] : P[0][dd]);
    float ymax = q[0];
    #pragma unroll
    for (int dd = 1; dd < 9; ++dd) ymax = fmaxf(ymax, q[dd]);
    float e[9];
    #pragma unroll
    for (int dd = 0; dd < 9; ++dd) e[dd] = __expf(q[dd] - ymax);
    float S = e[0];
    #pragma unroll
    for (int dd = 1; dd < 9; ++dd) S += e[dd];
    const float rinv = 1.0f / S;
    float s[9];
    #pragma unroll
    for (int dd = 0; dd < 9; ++dd) s[dd] = e[dd] * rinv;
    float smax = s[0], s2nd = -1.f; int sarg = 0;
    #pragma unroll
    for (int dd = 1; dd < 9; ++dd) {
      const bool g = s[dd] > smax;
      s2nd = g ? smax : ((s[dd] > s2nd) ? s[dd] : s2nd);
      smax = g ? s[dd] : smax;
      sarg = g ? dd : sarg;
    }
    {
      float x01 = sb0 ? s[1] : s[0], x23 = sb0 ? s[3] : s[2];
      float x45 = sb0 ? s[5] : s[4], x67 = sb0 ? s[7] : s[6];
      float y03 = sb1 ? x23 : x01, y47 = sb1 ? x67 : x45;
      float z07 = sb2 ? y47 : y03;
      float ssel = sb3 ? s[8] : z07;
      int usel = (rr3 == 1) ? u1 : ((rr3 == 2) ? u2 : u0);
      if (sv) sful[usel][dl] = ssel;
      if (rr3 < 3 && dl == 0) rgapL[usel] = smax - s2nd;
    }
    const float sc0 = __int_as_float(__builtin_amdgcn_readlane(__float_as_int(smax), 0));
    const float sc1 = __int_as_float(__builtin_amdgcn_readlane(__float_as_int(smax), 16));
    const float sc2 = __int_as_float(__builtin_amdgcn_readlane(__float_as_int(smax), 32));
    const int a0 = __builtin_amdgcn_readlane(sarg, 0);
    const int a1 = __builtin_amdgcn_readlane(sarg, 16);
    const int a2 = __builtin_amdgcn_readlane(sarg, 32);
    myscoreA = (distA == u0) ? sc0 : myscoreA;
    myscoreA = (distA == u1) ? sc1 : myscoreA;
    myscoreA = (distA == u2) ? sc2 : myscoreA;
    mydigA   = (distA == u0) ? a0 : mydigA;
    mydigA   = (distA == u1) ? a1 : mydigA;
    mydigA   = (distA == u2) ? a2 : mydigA;
    myscoreB = (distB == u0) ? sc0 : myscoreB;
    myscoreB = (distB == u1) ? sc1 : myscoreB;
    myscoreB = (distB == u2) ? sc2 : myscoreB;
    mydigB   = (distB == u0) ? a0 : mydigB;
    mydigB   = (distB == u1) ? a1 : mydigB;
    mydigB   = (distB == u2) ? a2 : mydigB;
    cbar();
  };

  // ---- slow path: fp64 row resolve from exact counts (rare) ----
  auto resolve_row = [&](int u, int& dig) -> double {
    int g, gia, gib, gic;
    grp_map(u, g, gia, gib, gic);
    const float* f0 = &cnt[g][gia][0];
    const float* f1 = &cnt[g][gib][0];
    const float* f2 = &cnt[g][gic][0];
    double p0 = 0.0, p1 = 0.0;
    #pragma unroll
    for (int c = 0; c < 9; ++c) {
      const double fv = (double)f0[c];
      p0 = fma(fv, (double)w1a[c], p0); p1 = fma(fv, (double)w1b[c], p1);
    }
    #pragma unroll
    for (int c = 0; c < 9; ++c) {
      const double fv = (double)f1[c];
      p0 = fma(fv, (double)w1a[9 + c], p0); p1 = fma(fv, (double)w1b[9 + c], p1);
    }
    #pragma unroll
    for (int c = 0; c < 9; ++c) {
      const double fv = (double)f2[c];
      p0 = fma(fv, (double)w1a[18 + c], p0); p1 = fma(fv, (double)w1b[18 + c], p1);
    }
    h64[lane]      = fmax(p0, 0.0);
    h64[64 + lane] = fmax(p1, 0.0);
    wave_fence();
    double y = -1e300;
    if (lane < 9) {
      double acc = 0.0;
      const double2* hp = (const double2*)h64;
      const float4* wp = (const float4*)&W2s[lane][0];
      #pragma unroll 4
      for (int k = 0; k < 32; ++k) {
        const double2 a = hp[2 * k];
        const double2 c2 = hp[2 * k + 1];
        const float4 w = wp[k];
        acc = fma(a.x,  (double)w.x, acc);
        acc = fma(a.y,  (double)w.y, acc);
        acc = fma(c2.x, (double)w.z, acc);
        acc = fma(c2.y, (double)w.w, acc);
      }
      y = acc;
    }
    double ymax = y;
    #pragma unroll
    for (int m = 1; m < 64; m <<= 1) ymax = fmax(ymax, __shfl_xor(ymax, m));
    const double ev = (lane < 9) ? exp(y - ymax) : 0.0;
    double S = ev;
    #pragma unroll
    for (int m = 1; m < 64; m <<= 1) S += __shfl_xor(S, m);
    const double s = (lane < 9) ? (ev / S) : -1.0;
    double smax = s;
    #pragma unroll
    for (int m = 1; m < 64; m <<= 1) smax = fmax(smax, __shfl_xor(smax, m));
    const unsigned long long bm = __ballot(s == smax);
    dig = __builtin_ctzll(bm);
    return smax;
  };

  // ---- initial 21 rows (fresh fp32 sequential dots) ----
  #pragma unroll 1
  for (int p = 0; p < 7; ++p) {
    const int U0 = 3 * p;
    #pragma unroll
    for (int rr = 0; rr < 3; ++rr) {
      const int u = U0 + rr;
      int g, gia, gib, gic;
      grp_map(u, g, gia, gib, gic);
      const float* f0 = &cnt[g][gia][0];
      const float* f1 = &cnt[g][gib][0];
      const float* f2 = &cnt[g][gic][0];
      float acc0 = 0.f, acc1 = 0.f;
      #pragma unroll
      for (int c = 0; c < 9; ++c) {
        acc0 = fmaf(f0[c], w1a[c], acc0); acc1 = fmaf(f0[c], w1b[c], acc1);
      }
      #pragma unroll
      for (int c = 0; c < 9; ++c) {
        acc0 = fmaf(f1[c], w1a[9 + c], acc0); acc1 = fmaf(f1[c], w1b[9 + c], acc1);
      }
      #pragma unroll
      for (int c = 0; c < 9; ++c) {
        acc0 = fmaf(f2[c], w1a[18 + c], acc0); acc1 = fmaf(f2[c], w1b[18 + c], acc1);
      }
      float2 pw; pw.x = acc0; pw.y = acc1;
      *(float2*)&preL[u][2 * lane] = pw;
      hA[rr] = fmaxf(acc0, 0.f);
      hB[rr] = fmaxf(acc1, 0.f);
    }
    cbar();
    phaseD(U0, U0 + 1, U0 + 2);
  }

  const float THR = 1e-3f;

  // ---- solver steps ----
  #pragma unroll 1
  for (int step = 0; step < 81; ++step) {
    const float sA = eA ? myscoreA : 0.f;
    const float sB = (lane < 17 && eB) ? myscoreB : 0.f;
    const float M = redmax64(fmaxf(sA, sB));
    if (M <= 0.f) break;

    // ---- near-tie safety net ----
    const bool cA = (sA > 0.f) && (sA >= M - THR);
    const bool cB = (sB > 0.f) && (sB >= M - THR);
    const unsigned long long candA = __ballot(cA);
    const unsigned long long candB = __ballot(cB) & 0x1FFFFull;
    const int firstC = candA ? __builtin_ctzll(candA) : 64 + __builtin_ctzll(candB);
    const int uf = dist_row(firstC);
    const unsigned long long diffA = __ballot(cA && (distA != uf));
    const unsigned long long diffB = __ballot(cB && (distB != uf));
    const bool multirow = (diffA | diffB) != 0ull;

    int mmax, digit;
    if (!multirow) {
      mmax = firstC;  // all candidates share row uf => identical scores => lowest idx
      const float gap = rgapL[uf];
      if (gap > THR) {
        const int dA_ = __builtin_amdgcn_readlane(mydigA, mmax & 63);
        const int dB_ = __builtin_amdgcn_readlane(mydigB, mmax & 63);
        digit = (mmax < 64) ? dA_ : dB_;
      } else {
        resolve_row(uf, digit);  // fp64 digit decision
      }
    } else {
      // resolve every distinct candidate row in fp64
      double csA = -1.0, csB = -1.0;
      int dgA = 0, dgB = 0;
      unsigned long long mA = candA, mB = candB;
      #pragma unroll 1
      while (mA | mB) {
        const int idx = mA ? __builtin_ctzll(mA) : 64 + __builtin_ctzll(mB);
        const int u = dist_row(idx);
        int dg;
        const double sc = resolve_row(u, dg);
        const bool hitA = ((mA >> lane) & 1ull) && (distA == u);
        const bool hitB = (lane < 17) && ((mB >> lane) & 1ull) && (distB == u);
        if (hitA) { csA = sc; dgA = dg; }
        if (hitB) { csB = sc; dgB = dg; }
        mA &= ~__ballot(hitA);
        mB &= ~(__ballot(hitB) & 0x1FFFFull);
      }
      double mm = fmax(csA, csB);
      #pragma unroll
      for (int m = 1; m < 64; m <<= 1) mm = fmax(mm, __shfl_xor(mm, m));
      const unsigned long long wAm = __ballot(csA == mm);
      const unsigned long long wBm = __ballot((lane < 17) && (csB == mm));
      mmax = wAm ? __builtin_ctzll(wAm) : 64 + __builtin_ctzll(wBm);
      digit = (mmax < 64) ? __builtin_amdgcn_readlane(dgA, mmax)
                          : __builtin_amdgcn_readlane(dgB, mmax - 64);
    }

    const int du = dist_row(mmax);
    const int r = mmax / 9, c = mmax - 9 * r;
    const int bx = (mmax / 27) * 3 + c / 3;
    const int q3 = c - 3 * (c / 3);

    // Phase B: output write, count update, empty-flag clear
    if (lane < 3) {
      const int gi = (lane == 0) ? r : (lane == 1) ? c : bx;
      cnt[lane][gi][digit] += 1.f;
    } else if (lane >= 8 && lane < 17) {
      ob[mmax * 9 + (lane - 8)] = sful[du][lane - 8];
    }
    if (lane == mmax) eA = false;
    if (lane + 64 == mmax) eB = false;
    wave_fence();

    // Phase C: incremental fp32 pre update
    const int u0 = r, u1 = 9 + c / 3, u2 = 12 + bx;
    {
      const bool b0d = digit & 1, b1d = digit & 2, b2d = digit & 4, b3d = digit & 8;
      const float ca0 = SEL9C(w1a, 0), ca1 = SEL9C(w1a, 9), ca2 = SEL9C(w1a, 18);
      const float cb0 = SEL9C(w1b, 0), cb1 = SEL9C(w1b, 9), cb2 = SEL9C(w1b, 18);
      const float d02a = ca0 + ca1 + ca2, d02b = cb0 + cb1 + cb2;
      const float d1a = (q3 == 0) ? ca0 : ((q3 == 1) ? ca1 : ca2);
      const float d1b = (q3 == 0) ? cb0 : ((q3 == 1) ? cb1 : cb2);
      float2 p0 = *(float2*)&preL[u0][2 * lane];
      float2 p1 = *(float2*)&preL[u1][2 * lane];
      float2 p2 = *(float2*)&preL[u2][2 * lane];
      p0.x += d02a; p0.y += d02b;
      p1.x += d1a;  p1.y += d1b;
      p2.x += d02a; p2.y += d02b;
      *(float2*)&preL[u0][2 * lane] = p0;
      *(float2*)&preL[u1][2 * lane] = p1;
      *(float2*)&preL[u2][2 * lane] = p2;
      hA[0] = fmaxf(p0.x, 0.f); hB[0] = fmaxf(p0.y, 0.f);
      hA[1] = fmaxf(p1.x, 0.f); hB[1] = fmaxf(p1.y, 0.f);
      hA[2] = fmaxf(p2.x, 0.f); hB[2] = fmaxf(p2.y, 0.f);
    }
    cbar();
    phaseD(u0, u1, u2);
  }
}

extern "C" void kernel_launch(void* const* d_in, const int* in_sizes, int n_in,
                              void* d_out, int out_size, void* d_ws, size_t ws_size,
                              hipStream_t stream) {
  const float* x  = (const float*)d_in[0];   // [2048][81][9]
  const float* W1 = (const float*)d_in[1];   // [128][27]
  const float* W2 = (const float*)d_in[2];   // [9][128]
  float* out = (float*)d_out;                // [2048][81][9]
  sudoku_solver<<<dim3(2048), dim3(64), 0, stream>>>(x, W1, W2, out);
}

// Round 7
// 301.102 us; speedup vs baseline: 1.6000x; 1.6000x over previous
//
#include <hip/hip_runtime.h>
#include <cstdint>
#include <cmath>

// Sudoku iterative-solver, one wave (64 lanes) per board — ALL-FP64 decisions.
// R1-R5 lessons baked in:
//  - 21 distinct f-rows; dist_row mapping; 3-row update set; ballot+ctz
//    first-max tie-break; cached-row reuse is bit-exact (verified vs np).
//  - R4: fp32 decisions flip vs np-fp64 (gaps ~1e-6). R5: fp64 fallback
//    correct but trigger machinery caused spills (WRITE_SIZE 6->22MB) + 2.3x.
//  - R6 (resubmit; prior round hit GPU-acquisition timeout, never ran):
//    uniform fp64 everywhere it matters, no triggers:
//      * fresh fp64 h per update from exact integer counts (no pre cache,
//        LDS ~17KB, no serial fp64 loops, no spills)
//      * Phase D via LDS scatter pp[27][65] + 27 owner-lane serial sums
//      * distributed softmax: one fp64 exp per (row,digit) owner lane
//      * scores fp64 in registers; digits via rargsL LDS

__device__ __forceinline__ void wave_fence() {
  asm volatile("s_waitcnt lgkmcnt(0)" ::: "memory");
}

__device__ __forceinline__ int dist_row(int i) {
  int r = i / 27;
  int t = i - 27 * r;
  if (r == 0) return t / 3;
  if (r == 1) return 9 + (t % 3);
  return 12 + 3 * (t / 9) + (t % 3);
}

__global__ __launch_bounds__(64, 2)
void sudoku_solver(const float* __restrict__ x, const float* __restrict__ W1g,
                   const float* __restrict__ W2g, float* __restrict__ out) {
  __shared__ double pp[27][65];     // Phase-D partials; pad 65 -> <=2-way banks
  __shared__ float  cnt[3][9][12];  // exact integer digit counts (fp32)
  __shared__ float  sful[21][12];   // cached softmax rows (fp32 of fp64)
  __shared__ int    rargsL[24];     // per-row argmax digit
  __shared__ int    digc[81];

  const int lane = threadIdx.x;     // 0..63
  const int b = blockIdx.x;
  const float* xb = x + b * 729;
  float* ob = out + b * 729;

  // ---- W1 rows in fp32 registers (exact inputs; cvt to f64 at use) ----
  float w1a[27], w1b[27];
  #pragma unroll
  for (int c = 0; c < 27; ++c) {
    w1a[c] = W1g[lane * 27 + c];
    w1b[c] = W1g[(lane + 64) * 27 + c];
  }
  // ---- W2 columns as fp64 registers ----
  double w2Ad[9], w2Bd[9];
  #pragma unroll
  for (int d = 0; d < 9; ++d) {
    w2Ad[d] = (double)W2g[d * 128 + lane];
    w2Bd[d] = (double)W2g[d * 128 + 64 + lane];
  }

  for (int idx = lane; idx < 3 * 9 * 12; idx += 64)
    ((float*)cnt)[idx] = 0.f;

  // ---- read board, ob = x, extract digits, empty flags ----
  bool eA, eB = false;
  {
    float v[9]; int dg = -1;
    #pragma unroll
    for (int e = 0; e < 9; ++e) v[e] = xb[lane * 9 + e];
    #pragma unroll
    for (int e = 0; e < 9; ++e) { if (v[e] > 0.5f) dg = e; ob[lane * 9 + e] = v[e]; }
    eA = (dg < 0); digc[lane] = dg;
    if (lane < 17) {
      const int i2 = 64 + lane;
      float w[9]; int dg2 = -1;
      #pragma unroll
      for (int e = 0; e < 9; ++e) w[e] = xb[i2 * 9 + e];
      #pragma unroll
      for (int e = 0; e < 9; ++e) { if (w[e] > 0.5f) dg2 = e; ob[i2 * 9 + e] = w[e]; }
      eB = (dg2 < 0); digc[i2] = dg2;
    }
  }
  const int distA = dist_row(lane);
  const int distB = (lane < 17) ? dist_row(64 + lane) : 255;
  const int rr3 = lane >> 4;        // 0..3 (3 = spare group)
  const int dl  = lane & 15;        // 0..15 (>8 invalid)
  const bool sv = (rr3 < 3) && (dl < 9);
  const int slot = rr3 * 9 + dl;    // valid only when sv
  wave_fence();

  // ---- initial group counts (27 lanes) ----
  if (lane < 27) {
    const int g = lane / 9, gi = lane - 9 * g;
    float c9[9];
    #pragma unroll
    for (int e = 0; e < 9; ++e) c9[e] = 0.f;
    #pragma unroll
    for (int k = 0; k < 9; ++k) {
      int cell;
      if (g == 0)      cell = gi * 9 + k;
      else if (g == 1) cell = k * 9 + gi;
      else             cell = (gi / 3) * 27 + (gi % 3) * 3 + (k / 3) * 9 + (k % 3);
      const int dg = digc[cell];
      #pragma unroll
      for (int e = 0; e < 9; ++e) c9[e] += (dg == e) ? 1.f : 0.f;
    }
    #pragma unroll
    for (int e = 0; e < 9; ++e) cnt[g][gi][e] = c9[e];
  }
  wave_fence();

  double myscoreA = 0.0, myscoreB = 0.0;

  // ---- update 3 rows: fresh fp64 MLP + LDS-reduce + distributed softmax ----
  auto update_rows = [&](int u0, int u1, int u2) {
    double hA[3], hB[3];
    #pragma unroll
    for (int rr = 0; rr < 3; ++rr) {
      const int u = (rr == 0) ? u0 : (rr == 1) ? u1 : u2;
      int g, gia, gib, gic;
      if (u < 9)       { g = 0; gia = gib = gic = u; }
      else if (u < 12) { g = 1; gia = 3 * (u - 9); gib = gia + 1; gic = gia + 2; }
      else             { g = 2; gia = gib = gic = u - 12; }
      const float* f0 = &cnt[g][gia][0];
      const float* f1 = &cnt[g][gib][0];
      const float* f2 = &cnt[g][gic][0];
      double a0 = 0.0, a1 = 0.0;
      #pragma unroll
      for (int c = 0; c < 9; ++c) {
        const double fv = (double)f0[c];
        a0 = fma(fv, (double)w1a[c], a0); a1 = fma(fv, (double)w1b[c], a1);
      }
      #pragma unroll
      for (int c = 0; c < 9; ++c) {
        const double fv = (double)f1[c];
        a0 = fma(fv, (double)w1a[9 + c], a0); a1 = fma(fv, (double)w1b[9 + c], a1);
      }
      #pragma unroll
      for (int c = 0; c < 9; ++c) {
        const double fv = (double)f2[c];
        a0 = fma(fv, (double)w1a[18 + c], a0); a1 = fma(fv, (double)w1b[18 + c], a1);
      }
      hA[rr] = fmax(a0, 0.0);
      hB[rr] = fmax(a1, 0.0);
    }

    // scatter per-lane fp64 partials: pp[row*9+digit][lane]
    #pragma unroll
    for (int rr = 0; rr < 3; ++rr)
      #pragma unroll
      for (int dd = 0; dd < 9; ++dd)
        pp[rr * 9 + dd][lane] = fma(hA[rr], w2Ad[dd], hB[rr] * w2Bd[dd]);
    wave_fence();

    // owner-lane reduce (sequential g — deterministic)
    double y = -1.0e300;
    if (sv) {
      double acc = 0.0;
      #pragma unroll 16
      for (int g = 0; g < 64; ++g) acc += pp[slot][g];
      y = acc;
    }

    // distributed softmax within each 16-lane group
    double ymax = y;
    ymax = fmax(ymax, __shfl_xor(ymax, 1));
    ymax = fmax(ymax, __shfl_xor(ymax, 2));
    ymax = fmax(ymax, __shfl_xor(ymax, 4));
    ymax = fmax(ymax, __shfl_xor(ymax, 8));
    const double ev = sv ? exp(y - ymax) : 0.0;
    double S = ev;
    S += __shfl_xor(S, 1);
    S += __shfl_xor(S, 2);
    S += __shfl_xor(S, 4);
    S += __shfl_xor(S, 8);
    const double s = ev / S;                 // NaN on spare group: discarded
    const double scmp = sv ? s : -1.0;
    double smax = scmp;
    smax = fmax(smax, __shfl_xor(smax, 1));
    smax = fmax(smax, __shfl_xor(smax, 2));
    smax = fmax(smax, __shfl_xor(smax, 4));
    smax = fmax(smax, __shfl_xor(smax, 8));
    const unsigned long long bm = __ballot(scmp == smax);
    const int u_sel = (rr3 == 1) ? u1 : ((rr3 == 2) ? u2 : u0);
    if (sv) sful[u_sel][dl] = (float)s;
    if (rr3 < 3 && dl == 0)
      rargsL[u_sel] = __builtin_ctz((unsigned)((bm >> (rr3 * 16)) & 0x1FFu));

    // broadcast the 3 row scores; refresh per-cell cached scores
    const double sc0 = __shfl(smax, 0);
    const double sc1 = __shfl(smax, 16);
    const double sc2 = __shfl(smax, 32);
    myscoreA = (distA == u0) ? sc0 : (distA == u1) ? sc1
             : (distA == u2) ? sc2 : myscoreA;
    myscoreB = (distB == u0) ? sc0 : (distB == u1) ? sc1
             : (distB == u2) ? sc2 : myscoreB;
    wave_fence();
  };

  // ---- initial 21 rows ----
  #pragma unroll 1
  for (int p = 0; p < 7; ++p) update_rows(3 * p, 3 * p + 1, 3 * p + 2);

  // ---- solver steps ----
  #pragma unroll 1
  for (int step = 0; step < 81; ++step) {
    // Phase A: fp64 wave argmax over empty cells (max score, first index)
    const double sA = eA ? myscoreA : 0.0;
    const double sB = (lane < 17 && eB) ? myscoreB : 0.0;
    double M = fmax(sA, sB);
    M = fmax(M, __shfl_xor(M, 1));
    M = fmax(M, __shfl_xor(M, 2));
    M = fmax(M, __shfl_xor(M, 4));
    M = fmax(M, __shfl_xor(M, 8));
    M = fmax(M, __shfl_xor(M, 16));
    M = fmax(M, __shfl_xor(M, 32));
    if (M <= 0.0) break;                    // uniform: board solved

    const unsigned long long m0 = __ballot(sA == M);
    const unsigned long long m1 = __ballot((lane < 17) && (sB == M));
    const int mmax = m0 ? __builtin_ctzll(m0) : 64 + __builtin_ctzll(m1);

    const int du = dist_row(mmax);
    const int digit = rargsL[du];           // LDS broadcast
    const int r = mmax / 9, c = mmax - 9 * r;
    const int bx = (mmax / 27) * 3 + c / 3;

    // Phase B: count update, output write, empty-flag clear
    if (lane < 3) {
      const int gi = (lane == 0) ? r : (lane == 1) ? c : bx;
      cnt[lane][gi][digit] += 1.f;
    } else if (lane >= 8 && lane < 17) {
      ob[mmax * 9 + (lane - 8)] = sful[du][lane - 8];
    }
    if (lane == mmax) eA = false;
    if (lane + 64 == mmax) eB = false;
    wave_fence();

    update_rows(r, 9 + c / 3, 12 + bx);
  }
}

extern "C" void kernel_launch(void* const* d_in, const int* in_sizes, int n_in,
                              void* d_out, int out_size, void* d_ws, size_t ws_size,
                              hipStream_t stream) {
  const float* x  = (const float*)d_in[0];   // [2048][81][9]
  const float* W1 = (const float*)d_in[1];   // [128][27]
  const float* W2 = (const float*)d_in[2];   // [9][128]
  float* out = (float*)d_out;                // [2048][81][9]
  sudoku_solver<<<dim3(2048), dim3(64), 0, stream>>>(x, W1, W2, out);
}